// Round 5
// baseline (388.076 us; speedup 1.0000x reference)
//
#include <hip/hip_runtime.h>
#include <hip/hip_bf16.h>

// MoE top-2 of 8: B=1024 tokens, M=10000, H=512.
// R5: bf16 pre-conversion of x/W1/W2 + global_load_lds (m97-style) GEMMs.
// Falls back to the proven R4 reg-staged path when ws is too small.

#define B_TOK 1024
#define M_DIM 10000
#define E_NUM 8
#define H_DIM 512
#define NSTEP 313  // ceil(10000/32)

typedef __attribute__((ext_vector_type(4))) float fx4;
typedef __attribute__((ext_vector_type(8))) short sx8;
typedef __attribute__((ext_vector_type(4))) short sx4;

#define LSTR 40           // R4 fallback LDS row stride (shorts)
#define BUFS (256 * LSTR)

__device__ __forceinline__ short f2bf(float f) {
  union { __hip_bfloat16 h; short s; } u;
  u.h = __float2bfloat16(f);
  return u.s;
}

__device__ __forceinline__ sx8 pack8(fx4 a, fx4 b) {
  sx8 r;
  r[0] = f2bf(a[0]); r[1] = f2bf(a[1]); r[2] = f2bf(a[2]); r[3] = f2bf(a[3]);
  r[4] = f2bf(b[0]); r[5] = f2bf(b[1]); r[6] = f2bf(b[2]); r[7] = f2bf(b[3]);
  return r;
}

__device__ __forceinline__ void gload16(const short* g, short* l) {
  __builtin_amdgcn_global_load_lds(
      (const __attribute__((address_space(1))) void*)g,
      (__attribute__((address_space(3))) void*)l, 16, 0, 0);
}

__global__ void k_zero(int* cnt, int* cnt2, int* zpad) {
  if (threadIdx.x < E_NUM) cnt[threadIdx.x] = 0;
  if (threadIdx.x < 2 * E_NUM) cnt2[threadIdx.x] = 0;
  if (threadIdx.x < 16) zpad[threadIdx.x] = 0;
}

// f32 -> bf16 bulk convert (n divisible by 2048*... launched with n/8 threads)
__global__ __launch_bounds__(256) void k_cvt(
    const float* __restrict__ src, short* __restrict__ dst)
{
  size_t i = ((size_t)blockIdx.x * 256 + threadIdx.x) * 8;
  fx4 a = *(const fx4*)(src + i);
  fx4 b = *(const fx4*)(src + i + 4);
  *(sx8*)(dst + i) = pack8(a, b);
}

// Router: f64-accumulated logits (top-2 flip safety vs numpy ref), softmax.
// Optionally writes x as bf16 (fused conversion).
__global__ __launch_bounds__(256) void k_router(
    const float* __restrict__ x, const float* __restrict__ Wr,
    int* __restrict__ cnt, int* __restrict__ cnt2,
    int* __restrict__ tokAll, int* __restrict__ qlist2, float* __restrict__ wlist2,
    short* __restrict__ xb)
{
  int b = blockIdx.x, t = threadIdx.x;
  const float* xr = x + (size_t)b * M_DIM;
  double acc[E_NUM];
#pragma unroll
  for (int e = 0; e < E_NUM; e++) acc[e] = 0.0;
  if (xb) {
    short* xbr = xb + (size_t)b * M_DIM;
    for (int m = t; m < M_DIM; m += 256) {
      float xv = xr[m];
      xbr[m] = f2bf(xv);
#pragma unroll
      for (int e = 0; e < E_NUM; e++)
        acc[e] += (double)xv * (double)Wr[e * M_DIM + m];
    }
  } else {
    for (int m = t; m < M_DIM; m += 256) {
      float xv = xr[m];
#pragma unroll
      for (int e = 0; e < E_NUM; e++)
        acc[e] += (double)xv * (double)Wr[e * M_DIM + m];
    }
  }
#pragma unroll
  for (int e = 0; e < E_NUM; e++) {
#pragma unroll
    for (int off = 32; off > 0; off >>= 1)
      acc[e] += __shfl_xor(acc[e], off);
  }
  __shared__ double part[4][E_NUM];
  int wave = t >> 6;
  if ((t & 63) == 0) {
    for (int e = 0; e < E_NUM; e++) part[wave][e] = acc[e];
  }
  __syncthreads();
  if (t == 0) {
    double lg[E_NUM];
    for (int e = 0; e < E_NUM; e++)
      lg[e] = part[0][e] + part[1][e] + part[2][e] + part[3][e];
    int i0 = 0;
    for (int e = 1; e < E_NUM; e++) if (lg[e] > lg[i0]) i0 = e;
    int i1 = (i0 == 0) ? 1 : 0;
    for (int e = 0; e < E_NUM; e++) if (e != i0 && lg[e] > lg[i1]) i1 = e;
    double ex = exp(lg[i1] - lg[i0]);
    float p0 = (float)(1.0 / (1.0 + ex));
    float p1 = (float)(ex / (1.0 + ex));
    int q0 = atomicAdd(&cnt[i0], 1);
    tokAll[i0 * B_TOK + q0] = b;
    int j0 = atomicAdd(&cnt2[i0 * 2 + 0], 1);
    qlist2[(i0 * 2 + 0) * B_TOK + j0] = q0;
    wlist2[(i0 * 2 + 0) * B_TOK + j0] = p0;
    int q1 = atomicAdd(&cnt[i1], 1);
    tokAll[i1 * B_TOK + q1] = b;
    int j1 = atomicAdd(&cnt2[i1 * 2 + 1], 1);
    qlist2[(i1 * 2 + 1) * B_TOK + j1] = q1;
    wlist2[(i1 * 2 + 1) * B_TOK + j1] = p1;
  }
}

// ---------- bf16 + global_load_lds GEMMs (m97 structure) ----------

// GEMM1 split-K: partials[kc][slot][col] = xb_gather . W1b[e]^T over chunk kc.
// 128x128 tile, BK=32, linear [128][32] bf16 LDS, dbuf, 1 barrier/step.
__global__ __launch_bounds__(256) void k_mlp1g(
    const short* __restrict__ xb, const short* __restrict__ Wb,
    const int* __restrict__ cnt, const int* __restrict__ tokAll,
    float* __restrict__ partials, const short* __restrict__ zpad, int CH)
{
  int e = blockIdx.z;
  int tt = blockIdx.y >> 2, nt = blockIdx.y & 3;
  int kc = blockIdx.x;

  __shared__ int sh_ne, sh_eoff;
  __shared__ __align__(16) short LA[2][4096];  // [buf][128 rows][32 cols]
  __shared__ __align__(16) short LB[2][4096];
  __shared__ int toks[128];

  int t = threadIdx.x;
  if (t == 0) {
    int off = 0;
    for (int k = 0; k < e; k++) off += cnt[k];
    sh_eoff = off; sh_ne = cnt[e];
  }
  __syncthreads();
  int ne = sh_ne, eoff = sh_eoff, row0 = tt * 128;
  if (row0 >= ne) return;
  int nvalid = min(128, ne - row0);
  if (t < 128) toks[t] = tokAll[e * B_TOK + row0 + min(t, nvalid - 1)];
  __syncthreads();

  int lane = t & 63, wave = t >> 6;
  // staging: wave w covers rows [w*32, w*32+32); lane l -> row +(l>>2), col8 (l&3)*8
  int srow = wave * 32 + (lane >> 2);
  int scol = (lane & 3) * 8;
  const short* ap0 = xb + (size_t)toks[srow] * M_DIM + scol;
  const short* ap1 = xb + (size_t)toks[srow + 16] * M_DIM + scol;
  const short* bp0 = Wb + ((size_t)e * H_DIM + nt * 128 + srow) * M_DIM + scol;
  const short* bp1 = bp0 + (size_t)16 * M_DIM;
  int ld0 = (wave * 32) * 32;        // LDS element offset, wave-uniform
  int ld1 = (wave * 32 + 16) * 32;

  int wr = wave >> 1, wc = wave & 1;
  int lrow = lane & 15, khalf = lane >> 4;

  fx4 z4 = {0.f, 0.f, 0.f, 0.f};
  fx4 acc[4][4];
#pragma unroll
  for (int m = 0; m < 4; m++)
#pragma unroll
    for (int n = 0; n < 4; n++) acc[m][n] = z4;

  int s0 = kc * CH, s1 = min(s0 + CH, NSTEP);

  {  // prologue: stage step s0 into buf 0
    int ko = s0 * 32;
    bool ok = (ko + scol + 8 <= M_DIM);
    gload16(ok ? (ap0 + ko) : zpad, LA[0] + ld0);
    gload16(ok ? (ap1 + ko) : zpad, LA[0] + ld1);
    gload16(ok ? (bp0 + ko) : zpad, LB[0] + ld0);
    gload16(ok ? (bp1 + ko) : zpad, LB[0] + ld1);
  }
  __syncthreads();

  int c = 0;
  for (int s = s0; s < s1; s++) {
    if (s + 1 < s1) {  // async prefetch of next step into the other buffer
      int ko = (s + 1) * 32;
      bool ok = (ko + scol + 8 <= M_DIM);
      int cn = c ^ 1;
      gload16(ok ? (ap0 + ko) : zpad, LA[cn] + ld0);
      gload16(ok ? (ap1 + ko) : zpad, LA[cn] + ld1);
      gload16(ok ? (bp0 + ko) : zpad, LB[cn] + ld0);
      gload16(ok ? (bp1 + ko) : zpad, LB[cn] + ld1);
    }
    sx8 af[4], bf[4];
#pragma unroll
    for (int m = 0; m < 4; m++)
      af[m] = *(const sx8*)(LA[c] + (wr * 64 + m * 16 + lrow) * 32 + khalf * 8);
#pragma unroll
    for (int n = 0; n < 4; n++)
      bf[n] = *(const sx8*)(LB[c] + (wc * 64 + n * 16 + lrow) * 32 + khalf * 8);
#pragma unroll
    for (int m = 0; m < 4; m++)
#pragma unroll
      for (int n = 0; n < 4; n++)
        acc[m][n] = __builtin_amdgcn_mfma_f32_16x16x32_bf16(af[m], bf[n], acc[m][n], 0, 0, 0);
    __syncthreads();  // drains vmcnt (gloads) + lgkm before buffer flip
    c ^= 1;
  }

#pragma unroll
  for (int m = 0; m < 4; m++)
#pragma unroll
    for (int n = 0; n < 4; n++) {
      int colg = nt * 128 + wc * 64 + n * 16 + lrow;
#pragma unroll
      for (int r = 0; r < 4; r++) {
        int rl = wr * 64 + m * 16 + khalf * 4 + r;
        if (rl < nvalid) {
          int grow = eoff + row0 + rl;
          partials[((size_t)kc * 2048 + grow) * H_DIM + colg] = acc[m][n][r];
        }
      }
    }
}

// GEMM2 pass (ord=0 overwrite, ord=1 accumulate), bf16 W2 + gload_lds.
__global__ __launch_bounds__(256) void k_mlp2g(
    const short* __restrict__ hbuf, const short* __restrict__ Wb,
    const float* __restrict__ b2, const int* __restrict__ cnt,
    const int* __restrict__ cnt2, const int* __restrict__ tokAll,
    const int* __restrict__ qlist2, const float* __restrict__ wlist2,
    float* __restrict__ out, int ord)
{
  int e = blockIdx.z, mt = blockIdx.y, tt = blockIdx.x;

  __shared__ int sh_ne2, sh_eoff;
  __shared__ __align__(16) short LA[2][4096];
  __shared__ __align__(16) short LB[2][4096];
  __shared__ int sl[128];
  __shared__ int tok2[128];
  __shared__ float wts[128];

  int t = threadIdx.x;
  if (t == 0) {
    int off = 0;
    for (int k = 0; k < e; k++) off += cnt[k];
    sh_eoff = off; sh_ne2 = cnt2[e * 2 + ord];
  }
  __syncthreads();
  int ne2 = sh_ne2, eoff = sh_eoff, row0 = tt * 128;
  if (row0 >= ne2) return;
  int nvalid = min(128, ne2 - row0);

  if (t < 128) {
    int j = row0 + min(t, nvalid - 1);
    int q = qlist2[(e * 2 + ord) * B_TOK + j];
    sl[t] = eoff + q;
    tok2[t] = tokAll[e * B_TOK + q];
    wts[t] = (t < nvalid) ? wlist2[(e * 2 + ord) * B_TOK + j] : 0.f;
  }
  __syncthreads();

  int lane = t & 63, wave = t >> 6;
  int srow = wave * 32 + (lane >> 2);
  int scol = (lane & 3) * 8;
  const short* ap0 = hbuf + (size_t)sl[srow] * H_DIM + scol;
  const short* ap1 = hbuf + (size_t)sl[srow + 16] * H_DIM + scol;
  const short* bp0 = Wb + ((size_t)e * M_DIM + min(mt * 128 + srow, M_DIM - 1)) * H_DIM + scol;
  const short* bp1 = Wb + ((size_t)e * M_DIM + min(mt * 128 + srow + 16, M_DIM - 1)) * H_DIM + scol;
  int ld0 = (wave * 32) * 32;
  int ld1 = (wave * 32 + 16) * 32;

  int wr = wave >> 1, wc = wave & 1;
  int lrow = lane & 15, khalf = lane >> 4;

  fx4 z4 = {0.f, 0.f, 0.f, 0.f};
  fx4 acc[4][4];
#pragma unroll
  for (int m = 0; m < 4; m++)
#pragma unroll
    for (int n = 0; n < 4; n++) acc[m][n] = z4;

  {  // prologue: step 0 -> buf 0 (K = 512 exact, no tail)
    gload16(ap0, LA[0] + ld0);
    gload16(ap1, LA[0] + ld1);
    gload16(bp0, LB[0] + ld0);
    gload16(bp1, LB[0] + ld1);
  }
  __syncthreads();

  int c = 0;
  for (int s = 0; s < 16; s++) {
    if (s + 1 < 16) {
      int ko = (s + 1) * 32;
      int cn = c ^ 1;
      gload16(ap0 + ko, LA[cn] + ld0);
      gload16(ap1 + ko, LA[cn] + ld1);
      gload16(bp0 + ko, LB[cn] + ld0);
      gload16(bp1 + ko, LB[cn] + ld1);
    }
    sx8 af[4], bf[4];
#pragma unroll
    for (int m = 0; m < 4; m++)
      af[m] = *(const sx8*)(LA[c] + (wr * 64 + m * 16 + lrow) * 32 + khalf * 8);
#pragma unroll
    for (int n = 0; n < 4; n++)
      bf[n] = *(const sx8*)(LB[c] + (wc * 64 + n * 16 + lrow) * 32 + khalf * 8);
#pragma unroll
    for (int m = 0; m < 4; m++)
#pragma unroll
      for (int n = 0; n < 4; n++)
        acc[m][n] = __builtin_amdgcn_mfma_f32_16x16x32_bf16(af[m], bf[n], acc[m][n], 0, 0, 0);
    __syncthreads();
    c ^= 1;
  }

#pragma unroll
  for (int m = 0; m < 4; m++)
#pragma unroll
    for (int n = 0; n < 4; n++) {
      int colg = mt * 128 + wc * 64 + n * 16 + lrow;
      if (colg < M_DIM) {
        float b2v = b2[(size_t)e * M_DIM + colg];
#pragma unroll
        for (int r = 0; r < 4; r++) {
          int rl = wr * 64 + m * 16 + khalf * 4 + r;
          if (rl < nvalid) {
            float v = wts[rl] * (acc[m][n][r] + b2v);
            float* dst = out + (size_t)tok2[rl] * M_DIM + colg;
            if (ord == 0) *dst = v;
            else *dst += v;
          }
        }
      }
    }
}

// Reduce split-K partials + bias + relu -> bf16 hbuf.
__global__ __launch_bounds__(256) void k_hreduce(
    const float* __restrict__ partials, const float* __restrict__ b1,
    const int* __restrict__ cnt, short* __restrict__ hbuf, int KC)
{
  __shared__ int sc[E_NUM];
  int t = threadIdx.x;
  if (t < E_NUM) sc[t] = cnt[t];
  __syncthreads();
  int i = (blockIdx.x * 256 + t) * 4;
  int slot = i >> 9;
  int e = 0, off = 0;
  for (int k = 0; k < E_NUM - 1; k++) {
    if (slot >= off + sc[k]) { off += sc[k]; e++; } else break;
  }
  fx4 v = *(const fx4*)(partials + i);
  for (int kc = 1; kc < KC; kc++)
    v += *(const fx4*)(partials + (size_t)kc * 2048 * H_DIM + i);
  fx4 bv = *(const fx4*)(b1 + e * H_DIM + (i & (H_DIM - 1)));
  sx4 o;
#pragma unroll
  for (int j = 0; j < 4; j++) o[j] = f2bf(fmaxf(v[j] + bv[j], 0.f));
  *(sx4*)(hbuf + i) = o;
}

// ---------- R4 fallback kernels (reg-staged f32) ----------

__global__ __launch_bounds__(256) void k_mlp1(
    const float* __restrict__ x, const float* __restrict__ W1,
    const int* __restrict__ cnt, const int* __restrict__ tokAll,
    float* __restrict__ partials, int CH)
{
  int e = blockIdx.z;
  int tt = blockIdx.y >> 2, nt = blockIdx.y & 3;
  int kc = blockIdx.x;

  __shared__ int sh_ne, sh_eoff;
  __shared__ __align__(16) short SB[2 * BUFS];
  __shared__ int toks[128];

  int t = threadIdx.x;
  if (t == 0) {
    int off = 0;
    for (int k = 0; k < e; k++) off += cnt[k];
    sh_eoff = off; sh_ne = cnt[e];
  }
  __syncthreads();
  int ne = sh_ne, eoff = sh_eoff, row0 = tt * 128;
  if (row0 >= ne) return;
  int nvalid = min(128, ne - row0);

  if (t < 128) toks[t] = tokAll[e * B_TOK + row0 + min(t, nvalid - 1)];
  __syncthreads();

  int r4 = t >> 2, kch = t & 3;
  const float* xr0 = x + (size_t)toks[r4] * M_DIM;
  const float* xr1 = x + (size_t)toks[r4 + 64] * M_DIM;
  const float* wr0 = W1 + ((size_t)e * H_DIM + nt * 128 + r4) * M_DIM;
  const float* wr1 = W1 + ((size_t)e * H_DIM + nt * 128 + r4 + 64) * M_DIM;

  int lane = t & 63, wave = t >> 6;
  int wr = wave >> 1, wc = wave & 1;
  int lrow = lane & 15, khalf = lane >> 4;

  fx4 z4 = {0.f, 0.f, 0.f, 0.f};
  fx4 acc[4][4];
#pragma unroll
  for (int m = 0; m < 4; m++)
#pragma unroll
    for (int n = 0; n < 4; n++) acc[m][n] = z4;

  int s0 = kc * CH, s1 = min(s0 + CH, NSTEP);
  sx8 zv = {0, 0, 0, 0, 0, 0, 0, 0};

  {
    int off = s0 * 32 + kch * 8;
    int oc = min(off, M_DIM - 8);
    bool ok = (off + 8 <= M_DIM);
    sx8 pa0 = ok ? pack8(*(const fx4*)(xr0 + oc), *(const fx4*)(xr0 + oc + 4)) : zv;
    sx8 pa1 = ok ? pack8(*(const fx4*)(xr1 + oc), *(const fx4*)(xr1 + oc + 4)) : zv;
    sx8 pb0 = ok ? pack8(*(const fx4*)(wr0 + oc), *(const fx4*)(wr0 + oc + 4)) : zv;
    sx8 pb1 = ok ? pack8(*(const fx4*)(wr1 + oc), *(const fx4*)(wr1 + oc + 4)) : zv;
    *(sx8*)(&SB[r4 * LSTR + kch * 8]) = pa0;
    *(sx8*)(&SB[(r4 + 64) * LSTR + kch * 8]) = pa1;
    *(sx8*)(&SB[(128 + r4) * LSTR + kch * 8]) = pb0;
    *(sx8*)(&SB[(128 + r4 + 64) * LSTR + kch * 8]) = pb1;
  }
  __syncthreads();

  int c = 0;
  for (int s = s0; s < s1; s++) {
    int off = (s + 1) * 32 + kch * 8;
    int oc = min(off, M_DIM - 8);
    bool okn = (off + 8 <= M_DIM);
    fx4 A0 = *(const fx4*)(xr0 + oc), A0b = *(const fx4*)(xr0 + oc + 4);
    fx4 A1 = *(const fx4*)(xr1 + oc), A1b = *(const fx4*)(xr1 + oc + 4);
    fx4 B0 = *(const fx4*)(wr0 + oc), B0b = *(const fx4*)(wr0 + oc + 4);
    fx4 B1 = *(const fx4*)(wr1 + oc), B1b = *(const fx4*)(wr1 + oc + 4);

    int bo = c * BUFS;
    sx8 af[4], bf[4];
#pragma unroll
    for (int m = 0; m < 4; m++)
      af[m] = *(const sx8*)(&SB[bo + (wr * 64 + m * 16 + lrow) * LSTR + khalf * 8]);
#pragma unroll
    for (int n = 0; n < 4; n++)
      bf[n] = *(const sx8*)(&SB[bo + (128 + wc * 64 + n * 16 + lrow) * LSTR + khalf * 8]);
#pragma unroll
    for (int m = 0; m < 4; m++)
#pragma unroll
      for (int n = 0; n < 4; n++)
        acc[m][n] = __builtin_amdgcn_mfma_f32_16x16x32_bf16(af[m], bf[n], acc[m][n], 0, 0, 0);

    if (s + 1 < s1) {
      int wo = (c ^ 1) * BUFS;
      sx8 pa0 = okn ? pack8(A0, A0b) : zv;
      sx8 pa1 = okn ? pack8(A1, A1b) : zv;
      sx8 pb0 = okn ? pack8(B0, B0b) : zv;
      sx8 pb1 = okn ? pack8(B1, B1b) : zv;
      *(sx8*)(&SB[wo + r4 * LSTR + kch * 8]) = pa0;
      *(sx8*)(&SB[wo + (r4 + 64) * LSTR + kch * 8]) = pa1;
      *(sx8*)(&SB[wo + (128 + r4) * LSTR + kch * 8]) = pb0;
      *(sx8*)(&SB[wo + (128 + r4 + 64) * LSTR + kch * 8]) = pb1;
    }
    __syncthreads();
    c ^= 1;
  }

#pragma unroll
  for (int m = 0; m < 4; m++)
#pragma unroll
    for (int n = 0; n < 4; n++) {
      int colg = nt * 128 + wc * 64 + n * 16 + lrow;
#pragma unroll
      for (int r = 0; r < 4; r++) {
        int rl = wr * 64 + m * 16 + khalf * 4 + r;
        if (rl < nvalid) {
          int grow = eoff + row0 + rl;
          partials[((size_t)kc * 2048 + grow) * H_DIM + colg] = acc[m][n][r];
        }
      }
    }
}

__global__ __launch_bounds__(256) void k_mlp2(
    const short* __restrict__ hbuf, const float* __restrict__ W2,
    const float* __restrict__ b2, const int* __restrict__ cnt,
    const int* __restrict__ cnt2, const int* __restrict__ tokAll,
    const int* __restrict__ qlist2, const float* __restrict__ wlist2,
    float* __restrict__ out, int ord)
{
  int e = blockIdx.z, mt = blockIdx.y, tt = blockIdx.x;

  __shared__ int sh_ne2, sh_eoff;
  __shared__ __align__(16) short SB[2 * BUFS];
  __shared__ int sl[128];
  __shared__ int tok2[128];
  __shared__ float wts[128];

  int t = threadIdx.x;
  if (t == 0) {
    int off = 0;
    for (int k = 0; k < e; k++) off += cnt[k];
    sh_eoff = off; sh_ne2 = cnt2[e * 2 + ord];
  }
  __syncthreads();
  int ne2 = sh_ne2, eoff = sh_eoff, row0 = tt * 128;
  if (row0 >= ne2) return;
  int nvalid = min(128, ne2 - row0);

  if (t < 128) {
    int j = row0 + min(t, nvalid - 1);
    int q = qlist2[(e * 2 + ord) * B_TOK + j];
    sl[t] = eoff + q;
    tok2[t] = tokAll[e * B_TOK + q];
    wts[t] = (t < nvalid) ? wlist2[(e * 2 + ord) * B_TOK + j] : 0.f;
  }
  __syncthreads();

  int r4 = t >> 2, kch = t & 3;
  const short* hr0 = hbuf + (size_t)sl[r4] * H_DIM;
  const short* hr1 = hbuf + (size_t)sl[r4 + 64] * H_DIM;
  const float* w20 = W2 + ((size_t)e * M_DIM + min(mt * 128 + r4, M_DIM - 1)) * H_DIM;
  const float* w21 = W2 + ((size_t)e * M_DIM + min(mt * 128 + r4 + 64, M_DIM - 1)) * H_DIM;

  int lane = t & 63, wave = t >> 6;
  int wr = wave >> 1, wc = wave & 1;
  int lrow = lane & 15, khalf = lane >> 4;

  fx4 z4 = {0.f, 0.f, 0.f, 0.f};
  fx4 acc[4][4];
#pragma unroll
  for (int m = 0; m < 4; m++)
#pragma unroll
    for (int n = 0; n < 4; n++) acc[m][n] = z4;

  {
    int off = kch * 8;
    sx8 pa0 = *(const sx8*)(hr0 + off);
    sx8 pa1 = *(const sx8*)(hr1 + off);
    fx4 B0 = *(const fx4*)(w20 + off), B0b = *(const fx4*)(w20 + off + 4);
    fx4 B1 = *(const fx4*)(w21 + off), B1b = *(const fx4*)(w21 + off + 4);
    *(sx8*)(&SB[r4 * LSTR + kch * 8]) = pa0;
    *(sx8*)(&SB[(r4 + 64) * LSTR + kch * 8]) = pa1;
    *(sx8*)(&SB[(128 + r4) * LSTR + kch * 8]) = pack8(B0, B0b);
    *(sx8*)(&SB[(128 + r4 + 64) * LSTR + kch * 8]) = pack8(B1, B1b);
  }
  __syncthreads();

  int c = 0;
  for (int s = 0; s < 16; s++) {
    int off = min((s + 1) * 32 + kch * 8, H_DIM - 8);
    sx8 pa0 = *(const sx8*)(hr0 + off);
    sx8 pa1 = *(const sx8*)(hr1 + off);
    fx4 B0 = *(const fx4*)(w20 + off), B0b = *(const fx4*)(w20 + off + 4);
    fx4 B1 = *(const fx4*)(w21 + off), B1b = *(const fx4*)(w21 + off + 4);

    int bo = c * BUFS;
    sx8 af[4], bf[4];
#pragma unroll
    for (int m = 0; m < 4; m++)
      af[m] = *(const sx8*)(&SB[bo + (wr * 64 + m * 16 + lrow) * LSTR + khalf * 8]);
#pragma unroll
    for (int n = 0; n < 4; n++)
      bf[n] = *(const sx8*)(&SB[bo + (128 + wc * 64 + n * 16 + lrow) * LSTR + khalf * 8]);
#pragma unroll
    for (int m = 0; m < 4; m++)
#pragma unroll
      for (int n = 0; n < 4; n++)
        acc[m][n] = __builtin_amdgcn_mfma_f32_16x16x32_bf16(af[m], bf[n], acc[m][n], 0, 0, 0);

    if (s + 1 < 16) {
      int wo = (c ^ 1) * BUFS;
      *(sx8*)(&SB[wo + r4 * LSTR + kch * 8]) = pa0;
      *(sx8*)(&SB[wo + (r4 + 64) * LSTR + kch * 8]) = pa1;
      *(sx8*)(&SB[wo + (128 + r4) * LSTR + kch * 8]) = pack8(B0, B0b);
      *(sx8*)(&SB[wo + (128 + r4 + 64) * LSTR + kch * 8]) = pack8(B1, B1b);
    }
    __syncthreads();
    c ^= 1;
  }

#pragma unroll
  for (int m = 0; m < 4; m++)
#pragma unroll
    for (int n = 0; n < 4; n++) {
      int colg = mt * 128 + wc * 64 + n * 16 + lrow;
      if (colg < M_DIM) {
        float b2v = b2[(size_t)e * M_DIM + colg];
#pragma unroll
        for (int r = 0; r < 4; r++) {
          int rl = wr * 64 + m * 16 + khalf * 4 + r;
          if (rl < nvalid) {
            float v = wts[rl] * (acc[m][n][r] + b2v);
            float* dst = out + (size_t)tok2[rl] * M_DIM + colg;
            if (ord == 0) *dst = v;
            else *dst += v;
          }
        }
      }
    }
}

extern "C" void kernel_launch(void* const* d_in, const int* in_sizes, int n_in,
                              void* d_out, int out_size, void* d_ws, size_t ws_size,
                              hipStream_t stream) {
  const float* x  = (const float*)d_in[0];
  const float* W1 = (const float*)d_in[1];
  const float* b1 = (const float*)d_in[2];
  const float* W2 = (const float*)d_in[3];
  const float* b2 = (const float*)d_in[4];
  const float* Wr = (const float*)d_in[5];
  float* out = (float*)d_out;

  const size_t NEED_BF16 = 138215616ULL;  // full bf16 path footprint
  int mode = (ws_size >= NEED_BF16) ? 1 : 0;

  if (mode == 1) {
    const int KC = 8, CH = (NSTEP + KC - 1) / KC;  // 40
    char* p = (char*)d_ws;
    float* partials = (float*)p;        p += (size_t)KC * 2048 * H_DIM * 4;  // 33,554,432
    short* hbuf     = (short*)p;        p += (size_t)2048 * H_DIM * 2;       // 2,097,152
    int*   cnt      = (int*)p;          p += 64;
    int*   cnt2     = (int*)p;          p += 64;
    int*   tokAll   = (int*)p;          p += E_NUM * B_TOK * 4;              // 32,768
    int*   qlist2   = (int*)p;          p += 2 * E_NUM * B_TOK * 4;          // 65,536
    float* wlist2   = (float*)p;        p += 2 * E_NUM * B_TOK * 4;          // 65,536
    int*   zpad     = (int*)p;          p += 64;
    short* xb       = (short*)p;        p += (size_t)B_TOK * M_DIM * 2;      // 20,480,000
    short* Wb       = (short*)p;                                             // 81,920,000

    k_zero<<<1, 64, 0, stream>>>(cnt, cnt2, zpad);
    k_router<<<B_TOK, 256, 0, stream>>>(x, Wr, cnt, cnt2, tokAll, qlist2, wlist2, xb);
    k_cvt<<<20000, 256, 0, stream>>>(W1, Wb);  // 8*512*10000 elems
    k_mlp1g<<<dim3(KC, 12, E_NUM), 256, 0, stream>>>(xb, Wb, cnt, tokAll, partials,
                                                     (const short*)zpad, CH);
    k_hreduce<<<1024, 256, 0, stream>>>(partials, b1, cnt, hbuf, KC);
    k_cvt<<<20000, 256, 0, stream>>>(W2, Wb);  // reuse buffer (stream-serial)
    k_mlp2g<<<dim3(2, 79, E_NUM), 256, 0, stream>>>(hbuf, Wb, b2, cnt, cnt2, tokAll,
                                                    qlist2, wlist2, out, 0);
    k_mlp2g<<<dim3(2, 79, E_NUM), 256, 0, stream>>>(hbuf, Wb, b2, cnt, cnt2, tokAll,
                                                    qlist2, wlist2, out, 1);
  } else {
    int KC = (ws_size >= (size_t)36 * 1024 * 1024) ? 8 : 4;
    int CH = (NSTEP + KC - 1) / KC;
    char* p = (char*)d_ws;
    float* partials = (float*)p;        p += (size_t)KC * 2048 * H_DIM * 4;
    short* hbuf     = (short*)p;        p += (size_t)2048 * H_DIM * 2;
    int*   cnt      = (int*)p;          p += 64;
    int*   cnt2     = (int*)p;          p += 64;
    int*   tokAll   = (int*)p;          p += E_NUM * B_TOK * 4;
    int*   qlist2   = (int*)p;          p += 2 * E_NUM * B_TOK * 4;
    float* wlist2   = (float*)p;        p += 2 * E_NUM * B_TOK * 4;
    int*   zpad     = (int*)p;

    k_zero<<<1, 64, 0, stream>>>(cnt, cnt2, zpad);
    k_router<<<B_TOK, 256, 0, stream>>>(x, Wr, cnt, cnt2, tokAll, qlist2, wlist2, nullptr);
    k_mlp1<<<dim3(KC, 12, E_NUM), 256, 0, stream>>>(x, W1, cnt, tokAll, partials, CH);
    k_hreduce<<<1024, 256, 0, stream>>>(partials, b1, cnt, hbuf, KC);
    k_mlp2<<<dim3(2, 79, E_NUM), 256, 0, stream>>>(hbuf, W2, b2, cnt, cnt2, tokAll,
                                                   qlist2, wlist2, out, 0);
    k_mlp2<<<dim3(2, 79, E_NUM), 256, 0, stream>>>(hbuf, W2, b2, cnt, cnt2, tokAll,
                                                   qlist2, wlist2, out, 1);
  }
}